// Round 11
// baseline (348.988 us; speedup 1.0000x reference)
//
#include <hip/hip_runtime.h>
#include <hip/hip_bf16.h>
#include <math.h>

#define B_ROWS 1024
#define NT 8192
#define NS 8192
#define DIM 1024
#define NC 10
#define TEMP 100.0f

typedef __bf16 bf16x8 __attribute__((ext_vector_type(8)));
typedef __bf16 bf16x4 __attribute__((ext_vector_type(4)));
typedef float f32x4 __attribute__((ext_vector_type(4)));

#define GLOAD_LDS(g, l) \
    __builtin_amdgcn_global_load_lds((__attribute__((address_space(1))) void*)(g), \
                                     (__attribute__((address_space(3))) void*)(l), 16, 0, 0)

__device__ inline __bf16 split_hi(float v) { return (__bf16)v; }
__device__ inline __bf16 split_lo(float v) {
    __bf16 h = (__bf16)v;
    return (__bf16)(v - (float)h);
}

// ---------------- reduction helpers ----------------
__device__ inline float wave_max(float v) {
    #pragma unroll
    for (int off = 32; off > 0; off >>= 1)
        v = fmaxf(v, __shfl_down(v, off, 64));
    return v;
}
__device__ inline float wave_sum(float v) {
    #pragma unroll
    for (int off = 32; off > 0; off >>= 1)
        v += __shfl_down(v, off, 64);
    return v;
}

// ---- wave-level: fp32 row (1024) -> bf16 hi/lo split + row norm -------------
// One 64-lane wave per row: 4 independent float4 loads/lane, no LDS, no barriers.
__device__ inline void conv_norm_row_wave(const float* __restrict__ X, int row,
                                          __bf16* __restrict__ X2,
                                          float* __restrict__ norms) {
    int lane = threadIdx.x & 63;
    const float4* xr = (const float4*)(X + (size_t)row * DIM);
    float4 v[4];
    #pragma unroll
    for (int i = 0; i < 4; i++) v[i] = xr[lane + 64 * i];
    __bf16* hr = X2 + (size_t)row * 2048;
    float acc = 0.f;
    #pragma unroll
    for (int i = 0; i < 4; i++) {
        bf16x4 h, l;
        h[0] = split_hi(v[i].x); l[0] = split_lo(v[i].x);
        h[1] = split_hi(v[i].y); l[1] = split_lo(v[i].y);
        h[2] = split_hi(v[i].z); l[2] = split_lo(v[i].z);
        h[3] = split_hi(v[i].w); l[3] = split_lo(v[i].w);
        int e = 4 * (lane + 64 * i);
        *(bf16x4*)(hr + e) = h;
        *(bf16x4*)(hr + 1024 + e) = l;
        acc += v[i].x * v[i].x + v[i].y * v[i].y + v[i].z * v[i].z + v[i].w * v[i].w;
    }
    acc = wave_sum(acc);
    if (lane == 0) norms[row] = acc;
}

// ---- K0: conv_norm(x) [0,256) + conv_norm(tf) [256,2304) + prep_labels ------
__global__ __launch_bounds__(256) void k_prep0(const float* __restrict__ x,
                                               const float* __restrict__ tf,
                                               const float* __restrict__ sld,
                                               const float* __restrict__ shdl,
                                               const float* __restrict__ atl,
                                               __bf16* __restrict__ x2,
                                               __bf16* __restrict__ tf2,
                                               float* __restrict__ nx_,
                                               float* __restrict__ nt_,
                                               float* __restrict__ M2Tt,
                                               float* __restrict__ atlt) {
    __shared__ float sldL[NC * NC];
    int b = blockIdx.x;
    int wid = threadIdx.x >> 6;
    if (b < 256) {
        conv_norm_row_wave(x, b * 4 + wid, x2, nx_);
    } else if (b < 256 + 2048) {
        conv_norm_row_wave(tf, (b - 256) * 4 + wid, tf2, nt_);
    } else {
        if (threadIdx.x < NC * NC) sldL[threadIdx.x] = sld[threadIdx.x];
        __syncthreads();
        int j = (b - 256 - 2048) * 256 + threadIdx.x;
        float sh[NC], at[NC];
        #pragma unroll
        for (int k = 0; k < NC; k++) sh[k] = shdl[(size_t)j * NC + k];
        #pragma unroll
        for (int c = 0; c < NC; c++) at[c] = atl[(size_t)j * NC + c];
        #pragma unroll
        for (int c = 0; c < NC; c++) {
            float t = 0.f;
            #pragma unroll
            for (int k = 0; k < NC; k++) t += sldL[c * NC + k] * sh[k];
            M2Tt[c * NS + j] = t;
            atlt[c * NS + j] = at[c];
        }
    }
}

// ---------------- 3-term split-bf16 MFMA GEMM: C = A*B^T ----------------
// MODE 0: atomicAdd fp32 accumulation into C[M][N] (split-K, no z offset)
// MODE 1: write logits  -TEMP*sqrt(rowN+colN-2*dot)
// 128x128 tile, BK=64; LDS row = 128B bank period; chunk XOR (row&7) conflict-free
template <int MODE>
__global__ __launch_bounds__(256) void k_gemm3(const __bf16* __restrict__ A2,
                                               const __bf16* __restrict__ B2,
                                               float* __restrict__ C,
                                               int M, int N, int K, int ksplit,
                                               const float* __restrict__ rowN,
                                               const float* __restrict__ colN) {
    __shared__ unsigned short AhS[8192], AlS[8192], BhS[8192], BlS[8192]; // 128x64 each
    __shared__ float extraL[MODE == 1 ? 256 : 2];
    float* rnL = extraL;
    float* cnL = extraL + 128;

    int tid = threadIdx.x;
    int wid = tid >> 6, lane = tid & 63;
    int wm = (wid >> 1) * 64, wn = (wid & 1) * 64;
    int id = blockIdx.y * gridDim.x + blockIdx.x;
    int bn_i = ((id >> 6) << 3) | (id & 7);
    int bm_i = (id >> 3) & 7;
    int bm = bm_i * 128, bn = bn_i * 128;
    size_t K2 = 2 * (size_t)K;
    int k_begin = blockIdx.z * ksplit;
    int nsteps = ksplit >> 6;

    if (MODE == 1) {
        if (tid < 128) rnL[tid] = rowN[bm + tid];
        else cnL[tid - 128] = colN[bn + tid - 128];
    }

    f32x4 acc[4][4];
    #pragma unroll
    for (int i = 0; i < 4; i++)
        #pragma unroll
        for (int j = 0; j < 4; j++) acc[i][j] = (f32x4){0.f, 0.f, 0.f, 0.f};

    int r_in = lane >> 3;
    int cgo = ((lane & 7) ^ r_in) * 8;
    const __bf16* gA = A2 + (size_t)(bm + wid * 32 + r_in) * K2 + k_begin + cgo;
    const __bf16* gB = B2 + (size_t)(bn + wid * 32 + r_in) * K2 + k_begin + cgo;
    char* AhB = (char*)AhS; char* AlB = (char*)AlS;
    char* BhB = (char*)BhS; char* BlB = (char*)BlS;
    int lbw = wid * 4096;
    size_t row8 = 8 * K2;

    int ra = lane & 15, q = lane >> 4;
    int aoff[4][2], boff[4][2];
    #pragma unroll
    for (int i = 0; i < 4; i++) {
        #pragma unroll
        for (int kh = 0; kh < 2; kh++) {
            int chunk = ((kh << 2) | q) ^ (ra & 7);
            aoff[i][kh] = (wm + i * 16 + ra) * 64 + chunk * 8;
            boff[i][kh] = (wn + i * 16 + ra) * 64 + chunk * 8;
        }
    }
    const __bf16* AhE = (const __bf16*)AhS;
    const __bf16* AlE = (const __bf16*)AlS;
    const __bf16* BhE = (const __bf16*)BhS;
    const __bf16* BlE = (const __bf16*)BlS;

    for (int ks = 0; ks < nsteps; ks++) {
        __syncthreads();
        #pragma unroll
        for (int p = 0; p < 4; p++) {
            size_t go = p * row8;
            int lo = lbw + p * 1024;
            GLOAD_LDS(gA + go, AhB + lo);
            GLOAD_LDS(gA + go + K, AlB + lo);
            GLOAD_LDS(gB + go, BhB + lo);
            GLOAD_LDS(gB + go + K, BlB + lo);
        }
        gA += 64; gB += 64;
        __syncthreads();

        #pragma unroll
        for (int kh = 0; kh < 2; kh++) {
            bf16x8 ah[4], al[4];
            #pragma unroll
            for (int mi = 0; mi < 4; mi++) {
                ah[mi] = *(const bf16x8*)(AhE + aoff[mi][kh]);
                al[mi] = *(const bf16x8*)(AlE + aoff[mi][kh]);
            }
            #pragma unroll
            for (int ni = 0; ni < 4; ni++) {
                bf16x8 bh = *(const bf16x8*)(BhE + boff[ni][kh]);
                bf16x8 bl = *(const bf16x8*)(BlE + boff[ni][kh]);
                #pragma unroll
                for (int mi = 0; mi < 4; mi++) {
                    acc[mi][ni] = __builtin_amdgcn_mfma_f32_16x16x32_bf16(ah[mi], bh, acc[mi][ni], 0, 0, 0);
                    acc[mi][ni] = __builtin_amdgcn_mfma_f32_16x16x32_bf16(ah[mi], bl, acc[mi][ni], 0, 0, 0);
                    acc[mi][ni] = __builtin_amdgcn_mfma_f32_16x16x32_bf16(al[mi], bh, acc[mi][ni], 0, 0, 0);
                }
            }
        }
    }

    if (MODE == 0) {
        #pragma unroll
        for (int mi = 0; mi < 4; mi++) {
            #pragma unroll
            for (int ni = 0; ni < 4; ni++) {
                int r0 = bm + wm + mi * 16 + q * 4;
                int c0 = bn + wn + ni * 16 + ra;
                #pragma unroll
                for (int i = 0; i < 4; i++)
                    atomicAdd(&C[(size_t)(r0 + i) * N + c0], acc[mi][ni][i]);
            }
        }
    } else {
        #pragma unroll
        for (int mi = 0; mi < 4; mi++) {
            #pragma unroll
            for (int ni = 0; ni < 4; ni++) {
                int cl = wn + ni * 16 + ra;
                float cn = cnL[cl];
                #pragma unroll
                for (int i = 0; i < 4; i++) {
                    int rl = wm + mi * 16 + q * 4 + i;
                    float sq = rnL[rl] + cn - 2.f * acc[mi][ni][i];
                    float d = sqrtf(fmaxf(sq, 1e-12f));
                    C[(size_t)(bm + rl) * N + bn + cl] = -TEMP * d;
                }
            }
        }
    }
}

// ---- K_mid: [0,1024): feature softmax S->w2 ; [1024,3072): conv2t asf->asfT2
__global__ __launch_bounds__(256) void k_mid(const float* __restrict__ S,
                                             const float* __restrict__ asf,
                                             __bf16* __restrict__ w2,
                                             __bf16* __restrict__ asfT2) {
    __shared__ float t[64][65];
    int b = blockIdx.x;
    if (b < B_ROWS) {
        int row = b;
        const float4* sr = (const float4*)(S + (size_t)row * NT);
        float4 vals[NT / 1024];
        float lmax = -1e30f;
        #pragma unroll
        for (int u = 0; u < NT / 1024; u++) {
            float4 v = sr[threadIdx.x + u * 256];
            vals[u] = v;
            lmax = fmaxf(fmaxf(fmaxf(v.x, v.y), fmaxf(v.z, v.w)), lmax);
        }
        float* sm = &t[0][0];
        float* ss = &t[1][0];
        int lane = threadIdx.x & 63, wid = threadIdx.x >> 6;
        float wm = wave_max(lmax);
        if (lane == 0) sm[wid] = wm;
        __syncthreads();
        float bmax = fmaxf(fmaxf(sm[0], sm[1]), fmaxf(sm[2], sm[3]));
        float lsum = 0.f;
        #pragma unroll
        for (int u = 0; u < NT / 1024; u++) {
            float4 v = vals[u];
            v.x = __expf(v.x - bmax); v.y = __expf(v.y - bmax);
            v.z = __expf(v.z - bmax); v.w = __expf(v.w - bmax);
            vals[u] = v;
            lsum += v.x + v.y + v.z + v.w;
        }
        float wsumv = wave_sum(lsum);
        if (lane == 0) ss[wid] = wsumv;
        __syncthreads();
        float inv = 1.0f / (ss[0] + ss[1] + ss[2] + ss[3]);
        __bf16* wr = w2 + (size_t)row * 16384;
        #pragma unroll
        for (int u = 0; u < NT / 1024; u++) {
            int j = (threadIdx.x + u * 256) * 4;
            float4 v = vals[u];
            v.x *= inv; v.y *= inv; v.z *= inv; v.w *= inv;
            bf16x4 h, l;
            h[0] = split_hi(v.x); l[0] = split_lo(v.x);
            h[1] = split_hi(v.y); l[1] = split_lo(v.y);
            h[2] = split_hi(v.z); l[2] = split_lo(v.z);
            h[3] = split_hi(v.w); l[3] = split_lo(v.w);
            *(bf16x4*)(wr + j) = h;
            *(bf16x4*)(wr + 8192 + j) = l;
        }
        return;
    }
    int bb = b - B_ROWS;
    int k0 = (bb >> 4) * 64;
    int n0 = (bb & 15) * 64;
    int tid = threadIdx.x;
    int tr = tid >> 4;
    int tc = (tid & 15) * 4;
    #pragma unroll
    for (int i = 0; i < 4; i++) {
        int r = tr + i * 16;
        float4 v = *(const float4*)(asf + (size_t)(k0 + r) * 1024 + n0 + tc);
        t[r][tc] = v.x; t[r][tc + 1] = v.y; t[r][tc + 2] = v.z; t[r][tc + 3] = v.w;
    }
    __syncthreads();
    #pragma unroll
    for (int i = 0; i < 4; i++) {
        int n = tr + i * 16;
        bf16x4 h, l;
        #pragma unroll
        for (int e = 0; e < 4; e++) {
            float v = t[tc + e][n];
            h[e] = split_hi(v);
            l[e] = split_lo(v);
        }
        size_t base = (size_t)(n0 + n) * 16384 + k0 + tc;
        *(bf16x4*)(asfT2 + base) = h;
        *(bf16x4*)(asfT2 + base + 8192) = l;
    }
}

// -- K_fuse2: [0,1024): read xsrcF + split + norm + preds
//             [1024,3072): conv_norm(sf) wave-per-row -> sf2
__global__ __launch_bounds__(256) void k_fuse2(const float* __restrict__ xsrcF,
                                               const float* __restrict__ sf,
                                               const float* __restrict__ W,
                                               const float* __restrict__ bias,
                                               __bf16* __restrict__ xsrc2,
                                               __bf16* __restrict__ sf2,
                                               float* __restrict__ nx2_,
                                               float* __restrict__ ns_,
                                               float* __restrict__ preds) {
    __shared__ float red[4][NC + 1];
    int b = blockIdx.x;
    if (b >= B_ROWS) {
        int wid = threadIdx.x >> 6;
        conv_norm_row_wave(sf, (b - B_ROWS) * 4 + wid, sf2, ns_);
        return;
    }
    int row = b;
    int c = threadIdx.x * 4;
    float4 s = *(const float4*)(xsrcF + (size_t)row * DIM + c);
    bf16x4 h, l;
    h[0] = split_hi(s.x); l[0] = split_lo(s.x);
    h[1] = split_hi(s.y); l[1] = split_lo(s.y);
    h[2] = split_hi(s.z); l[2] = split_lo(s.z);
    h[3] = split_hi(s.w); l[3] = split_lo(s.w);
    *(bf16x4*)(xsrc2 + (size_t)row * 2048 + c) = h;
    *(bf16x4*)(xsrc2 + (size_t)row * 2048 + 1024 + c) = l;
    float accn = s.x * s.x + s.y * s.y + s.z * s.z + s.w * s.w;
    float accp[NC];
    #pragma unroll
    for (int cc = 0; cc < NC; cc++)
        accp[cc] = s.x * W[(c + 0) * NC + cc] + s.y * W[(c + 1) * NC + cc]
                 + s.z * W[(c + 2) * NC + cc] + s.w * W[(c + 3) * NC + cc];
    accn = wave_sum(accn);
    #pragma unroll
    for (int cc = 0; cc < NC; cc++) accp[cc] = wave_sum(accp[cc]);
    int lane = threadIdx.x & 63, wid = threadIdx.x >> 6;
    if (lane == 0) {
        red[wid][0] = accn;
        #pragma unroll
        for (int cc = 0; cc < NC; cc++) red[wid][1 + cc] = accp[cc];
    }
    __syncthreads();
    if (threadIdx.x == 0) {
        nx2_[row] = red[0][0] + red[1][0] + red[2][0] + red[3][0];
        float lo[NC];
        float m = -1e30f;
        #pragma unroll
        for (int cc = 0; cc < NC; cc++) {
            lo[cc] = red[0][1 + cc] + red[1][1 + cc] + red[2][1 + cc] + red[3][1 + cc]
                   + bias[cc];
            m = fmaxf(m, lo[cc]);
        }
        float ssum = 0.f;
        #pragma unroll
        for (int cc = 0; cc < NC; cc++) {
            lo[cc] = __expf(lo[cc] - m);
            ssum += lo[cc];
        }
        float inv = 1.0f / ssum;
        #pragma unroll
        for (int cc = 0; cc < NC; cc++) preds[(size_t)row * NC + cc] = lo[cc] * inv;
    }
}

// ------- label softmax + y, 2 rows/block, 512 threads, float4-vectorized -----
__global__ __launch_bounds__(512) void k_lab_softmax_y(const float* __restrict__ S,
                                                       const float* __restrict__ predsG,
                                                       const float* __restrict__ M2Tt,
                                                       const float* __restrict__ atlt,
                                                       float* __restrict__ y) {
    int r0 = blockIdx.x * 2, r1 = r0 + 1;
    float pr0[NC], pr1[NC];
    #pragma unroll
    for (int c = 0; c < NC; c++) {
        pr0[c] = predsG[(size_t)r0 * NC + c];
        pr1[c] = predsG[(size_t)r1 * NC + c];
    }
    const float4* s0 = (const float4*)(S + (size_t)r0 * NS);
    const float4* s1 = (const float4*)(S + (size_t)r1 * NS);
    const float4* M2 = (const float4*)M2Tt;
    const float4* AT = (const float4*)atlt;
    float4 v0[NS / 2048], v1[NS / 2048];
    float m0 = -1e30f, m1 = -1e30f;
    #pragma unroll
    for (int u = 0; u < NS / 2048; u++) {
        int j4 = threadIdx.x + u * 512;
        float4 a = s0[j4], b = s1[j4];
        float4 lab0 = make_float4(0.f, 0.f, 0.f, 0.f);
        float4 lab1 = make_float4(0.f, 0.f, 0.f, 0.f);
        #pragma unroll
        for (int c = 0; c < NC; c++) {
            float4 mv = M2[c * 2048 + j4];
            lab0.x += pr0[c] * mv.x; lab0.y += pr0[c] * mv.y;
            lab0.z += pr0[c] * mv.z; lab0.w += pr0[c] * mv.w;
            lab1.x += pr1[c] * mv.x; lab1.y += pr1[c] * mv.y;
            lab1.z += pr1[c] * mv.z; lab1.w += pr1[c] * mv.w;
        }
        a.x -= TEMP * lab0.x; a.y -= TEMP * lab0.y;
        a.z -= TEMP * lab0.z; a.w -= TEMP * lab0.w;
        b.x -= TEMP * lab1.x; b.y -= TEMP * lab1.y;
        b.z -= TEMP * lab1.z; b.w -= TEMP * lab1.w;
        v0[u] = a; v1[u] = b;
        m0 = fmaxf(m0, fmaxf(fmaxf(a.x, a.y), fmaxf(a.z, a.w)));
        m1 = fmaxf(m1, fmaxf(fmaxf(b.x, b.y), fmaxf(b.z, b.w)));
    }
    __shared__ float sm[2][8];
    __shared__ float ss[2][8];
    __shared__ float yred[8][2][NC];
    int lane = threadIdx.x & 63, wid = threadIdx.x >> 6;
    float wm0 = wave_max(m0), wm1 = wave_max(m1);
    if (lane == 0) { sm[0][wid] = wm0; sm[1][wid] = wm1; }
    __syncthreads();
    float bm0 = -1e30f, bm1 = -1e30f;
    #pragma unroll
    for (int wq = 0; wq < 8; wq++) {
        bm0 = fmaxf(bm0, sm[0][wq]);
        bm1 = fmaxf(bm1, sm[1][wq]);
    }
    float ls0 = 0.f, ls1 = 0.f;
    #pragma unroll
    for (int u = 0; u < NS / 2048; u++) {
        float4 a = v0[u], b = v1[u];
        a.x = __expf(a.x - bm0); a.y = __expf(a.y - bm0);
        a.z = __expf(a.z - bm0); a.w = __expf(a.w - bm0);
        b.x = __expf(b.x - bm1); b.y = __expf(b.y - bm1);
        b.z = __expf(b.z - bm1); b.w = __expf(b.w - bm1);
        v0[u] = a; v1[u] = b;
        ls0 += a.x + a.y + a.z + a.w;
        ls1 += b.x + b.y + b.z + b.w;
    }
    float ws0 = wave_sum(ls0), ws1 = wave_sum(ls1);
    if (lane == 0) { ss[0][wid] = ws0; ss[1][wid] = ws1; }
    __syncthreads();
    float t0 = 0.f, t1 = 0.f;
    #pragma unroll
    for (int wq = 0; wq < 8; wq++) { t0 += ss[0][wq]; t1 += ss[1][wq]; }
    float inv0 = 1.0f / t0, inv1 = 1.0f / t1;
    float y0[NC] = {}, y1[NC] = {};
    #pragma unroll
    for (int u = 0; u < NS / 2048; u++) {
        int j4 = threadIdx.x + u * 512;
        float4 a = v0[u], b = v1[u];
        #pragma unroll
        for (int c = 0; c < NC; c++) {
            float4 av = AT[c * 2048 + j4];
            y0[c] += a.x * av.x + a.y * av.y + a.z * av.z + a.w * av.w;
            y1[c] += b.x * av.x + b.y * av.y + b.z * av.z + b.w * av.w;
        }
    }
    #pragma unroll
    for (int c = 0; c < NC; c++) {
        y0[c] = wave_sum(y0[c]) * inv0;
        y1[c] = wave_sum(y1[c]) * inv1;
    }
    if (lane == 0) {
        #pragma unroll
        for (int c = 0; c < NC; c++) { yred[wid][0][c] = y0[c]; yred[wid][1][c] = y1[c]; }
    }
    __syncthreads();
    if (threadIdx.x < 2 * NC) {
        int r = threadIdx.x / NC, c = threadIdx.x - r * NC;
        float acc = 0.f;
        #pragma unroll
        for (int wq = 0; wq < 8; wq++) acc += yred[wq][r][c];
        y[(size_t)(r0 + r) * NC + c] = acc;
    }
}

extern "C" void kernel_launch(void* const* d_in, const int* in_sizes, int n_in,
                              void* d_out, int out_size, void* d_ws, size_t ws_size,
                              hipStream_t stream) {
    const float* x    = (const float*)d_in[0];
    const float* tf   = (const float*)d_in[1];
    const float* asf  = (const float*)d_in[2];
    const float* sf   = (const float*)d_in[3];
    const float* shdl = (const float*)d_in[4];
    const float* atl  = (const float*)d_in[5];
    const float* sld  = (const float*)d_in[6];
    const float* W    = (const float*)d_in[7];
    const float* bias = (const float*)d_in[8];
    float* y = (float*)d_out;

    char* wsb = (char*)d_ws;
    // Region lifetimes (32 MiB each):
    //  R0 @0:  S (G1 out, read by k_mid) -> S (G3 out, read by k_lab)
    //  R1 @32: tf2 (until G1) -> asfT2 (k_mid out, until G2)
    //  R2 @64: w2 (until G2) -> sf2 (k_fuse2 out, until G3)
    //  xsrcF @104 (4 MiB): G2 atomic accumulator (zeroed at start)
    float*  S     = (float*)(wsb);
    __bf16* tf2   = (__bf16*)(wsb + (32u << 20));
    __bf16* asfT2 = (__bf16*)(wsb + (32u << 20));
    __bf16* w2    = (__bf16*)(wsb + (64u << 20));
    __bf16* sf2   = (__bf16*)(wsb + (64u << 20));
    __bf16* x2    = (__bf16*)(wsb + (96u << 20));
    __bf16* xsrc2 = (__bf16*)(wsb + (100u << 20));
    float*  xsrcF = (float*)(wsb + (104u << 20));
    float*  nt_   = (float*)(wsb + (108u << 20));
    float*  ns_   = nt_ + NT;
    float*  nx_   = ns_ + NS;
    float*  nx2_  = nx_ + B_ROWS;
    float*  preds = nx2_ + B_ROWS;
    float*  M2Tt  = preds + B_ROWS * NC;
    float*  atlt  = M2Tt + NS * NC;

    // zero the atomic accumulator (graph-capture-safe)
    hipMemsetAsync(xsrcF, 0, (size_t)B_ROWS * DIM * sizeof(float), stream);

    // K0: conv_norm(x) + conv_norm(tf) wave-per-row + prep_labels
    k_prep0<<<256 + 2048 + NS / 256, 256, 0, stream>>>(x, tf, sld, shdl, atl,
                                                       x2, tf2, nx_, nt_, M2Tt, atlt);

    // G1: S = logits(-TEMP*d(x, tf))
    {
        dim3 g(NT / 128, B_ROWS / 128, 1);
        k_gemm3<1><<<g, 256, 0, stream>>>(x2, tf2, S, B_ROWS, NT, DIM, DIM,
                                          nx_, nt_);
    }
    // K_mid: softmax(S)->w2 (R2)  +  conv2t(asf)->asfT2 (R1)
    k_mid<<<B_ROWS + 2048, 256, 0, stream>>>(S, asf, w2, asfT2);
    // G2: xsrcF += w2 @ asfT2^T  (split-K x8, atomic accumulation)
    {
        dim3 g(DIM / 128, B_ROWS / 128, 8);
        k_gemm3<0><<<g, 256, 0, stream>>>(w2, asfT2, xsrcF, B_ROWS, DIM, NT, NT / 8,
                                          nullptr, nullptr);
    }
    // K_fuse2: xsrcF -> split+norm+preds ; conv_norm(sf) wave-per-row -> R2
    k_fuse2<<<B_ROWS + 2048, 256, 0, stream>>>(xsrcF, sf, W, bias, xsrc2, sf2,
                                               nx2_, ns_, preds);

    // G3: S = logits(-TEMP*d(xsrc, sf))
    {
        dim3 g(NS / 128, B_ROWS / 128, 1);
        k_gemm3<1><<<g, 256, 0, stream>>>(xsrc2, sf2, S, B_ROWS, NS, DIM, DIM,
                                          nx2_, ns_);
    }
    // label softmax (with M2T term) + y
    k_lab_softmax_y<<<B_ROWS / 2, 512, 0, stream>>>(S, preds, M2Tt, atlt, y);
}

// Round 12
// 337.469 us; speedup vs baseline: 1.0341x; 1.0341x over previous
//
#include <hip/hip_runtime.h>
#include <hip/hip_bf16.h>
#include <math.h>

#define B_ROWS 1024
#define NT 8192
#define NS 8192
#define DIM 1024
#define NC 10
#define TEMP 100.0f

typedef __bf16 bf16x8 __attribute__((ext_vector_type(8)));
typedef __bf16 bf16x4 __attribute__((ext_vector_type(4)));
typedef float f32x4 __attribute__((ext_vector_type(4)));

#define GLOAD_LDS(g, l) \
    __builtin_amdgcn_global_load_lds((__attribute__((address_space(1))) void*)(g), \
                                     (__attribute__((address_space(3))) void*)(l), 16, 0, 0)

__device__ inline __bf16 split_hi(float v) { return (__bf16)v; }
__device__ inline __bf16 split_lo(float v) {
    __bf16 h = (__bf16)v;
    return (__bf16)(v - (float)h);
}

// ---------------- reduction helpers ----------------
__device__ inline float wave_max(float v) {
    #pragma unroll
    for (int off = 32; off > 0; off >>= 1)
        v = fmaxf(v, __shfl_down(v, off, 64));
    return v;
}
__device__ inline float wave_sum(float v) {
    #pragma unroll
    for (int off = 32; off > 0; off >>= 1)
        v += __shfl_down(v, off, 64);
    return v;
}

// ---- wave-level: fp32 row (1024) -> bf16 hi/lo split + row norm -------------
// One 64-lane wave per row: 4 independent float4 loads/lane, no LDS, no barriers.
__device__ inline void conv_norm_row_wave(const float* __restrict__ X, int row,
                                          __bf16* __restrict__ X2,
                                          float* __restrict__ norms) {
    int lane = threadIdx.x & 63;
    const float4* xr = (const float4*)(X + (size_t)row * DIM);
    float4 v[4];
    #pragma unroll
    for (int i = 0; i < 4; i++) v[i] = xr[lane + 64 * i];
    __bf16* hr = X2 + (size_t)row * 2048;
    float acc = 0.f;
    #pragma unroll
    for (int i = 0; i < 4; i++) {
        bf16x4 h, l;
        h[0] = split_hi(v[i].x); l[0] = split_lo(v[i].x);
        h[1] = split_hi(v[i].y); l[1] = split_lo(v[i].y);
        h[2] = split_hi(v[i].z); l[2] = split_lo(v[i].z);
        h[3] = split_hi(v[i].w); l[3] = split_lo(v[i].w);
        int e = 4 * (lane + 64 * i);
        *(bf16x4*)(hr + e) = h;
        *(bf16x4*)(hr + 1024 + e) = l;
        acc += v[i].x * v[i].x + v[i].y * v[i].y + v[i].z * v[i].z + v[i].w * v[i].w;
    }
    acc = wave_sum(acc);
    if (lane == 0) norms[row] = acc;
}

// ---- K0: conv_norm(x) [0,256) + conv_norm(tf) [256,2304) + prep_labels ------
__global__ __launch_bounds__(256) void k_prep0(const float* __restrict__ x,
                                               const float* __restrict__ tf,
                                               const float* __restrict__ sld,
                                               const float* __restrict__ shdl,
                                               const float* __restrict__ atl,
                                               __bf16* __restrict__ x2,
                                               __bf16* __restrict__ tf2,
                                               float* __restrict__ nx_,
                                               float* __restrict__ nt_,
                                               float* __restrict__ M2Tt,
                                               float* __restrict__ atlt) {
    __shared__ float sldL[NC * NC];
    int b = blockIdx.x;
    int wid = threadIdx.x >> 6;
    if (b < 256) {
        conv_norm_row_wave(x, b * 4 + wid, x2, nx_);
    } else if (b < 256 + 2048) {
        conv_norm_row_wave(tf, (b - 256) * 4 + wid, tf2, nt_);
    } else {
        if (threadIdx.x < NC * NC) sldL[threadIdx.x] = sld[threadIdx.x];
        __syncthreads();
        int j = (b - 256 - 2048) * 256 + threadIdx.x;
        float sh[NC], at[NC];
        #pragma unroll
        for (int k = 0; k < NC; k++) sh[k] = shdl[(size_t)j * NC + k];
        #pragma unroll
        for (int c = 0; c < NC; c++) at[c] = atl[(size_t)j * NC + c];
        #pragma unroll
        for (int c = 0; c < NC; c++) {
            float t = 0.f;
            #pragma unroll
            for (int k = 0; k < NC; k++) t += sldL[c * NC + k] * sh[k];
            M2Tt[c * NS + j] = t;
            atlt[c * NS + j] = at[c];
        }
    }
}

// ---- conv2t(asf): [8192][1024] -> transposed hi/lo split [1024][2*8192] -----
__global__ __launch_bounds__(256) void k_conv2t(const float* __restrict__ asf,
                                                __bf16* __restrict__ asfT2) {
    __shared__ float t[64][65];
    int b = blockIdx.x;
    int k0 = (b >> 4) * 64;
    int n0 = (b & 15) * 64;
    int tid = threadIdx.x;
    int tr = tid >> 4;
    int tc = (tid & 15) * 4;
    #pragma unroll
    for (int i = 0; i < 4; i++) {
        int r = tr + i * 16;
        float4 v = *(const float4*)(asf + (size_t)(k0 + r) * 1024 + n0 + tc);
        t[r][tc] = v.x; t[r][tc + 1] = v.y; t[r][tc + 2] = v.z; t[r][tc + 3] = v.w;
    }
    __syncthreads();
    #pragma unroll
    for (int i = 0; i < 4; i++) {
        int n = tr + i * 16;
        bf16x4 h, l;
        #pragma unroll
        for (int e = 0; e < 4; e++) {
            float v = t[tc + e][n];
            h[e] = split_hi(v);
            l[e] = split_lo(v);
        }
        size_t base = (size_t)(n0 + n) * 16384 + k0 + tc;
        *(bf16x4*)(asfT2 + base) = h;
        *(bf16x4*)(asfT2 + base + 8192) = l;
    }
}

// ---------------- 3-term split-bf16 MFMA GEMM: C = A*B^T ----------------
// LOGITS=false: plain fp32 C write (+ blockIdx.z * M*N partials)
// LOGITS=true:  write logits  -TEMP*sqrt(rowN+colN-2*dot)
// 128x128 tile, BK=64; LDS row = 128B bank period; chunk XOR (row&7) conflict-free
template <bool LOGITS>
__global__ __launch_bounds__(256) void k_gemm3(const __bf16* __restrict__ A2,
                                               const __bf16* __restrict__ B2,
                                               float* __restrict__ C,
                                               int M, int N, int K, int ksplit,
                                               const float* __restrict__ rowN,
                                               const float* __restrict__ colN) {
    __shared__ unsigned short AhS[8192], AlS[8192], BhS[8192], BlS[8192]; // 128x64 each
    __shared__ float extraL[LOGITS ? 256 : 2];
    float* rnL = extraL;
    float* cnL = extraL + 128;

    int tid = threadIdx.x;
    int wid = tid >> 6, lane = tid & 63;
    int wm = (wid >> 1) * 64, wn = (wid & 1) * 64;
    int id = blockIdx.y * gridDim.x + blockIdx.x;
    int bn_i = ((id >> 6) << 3) | (id & 7);
    int bm_i = (id >> 3) & 7;
    int bm = bm_i * 128, bn = bn_i * 128;
    size_t K2 = 2 * (size_t)K;
    int k_begin = blockIdx.z * ksplit;
    int nsteps = ksplit >> 6;

    if (LOGITS) {
        if (tid < 128) rnL[tid] = rowN[bm + tid];
        else cnL[tid - 128] = colN[bn + tid - 128];
    }

    f32x4 acc[4][4];
    #pragma unroll
    for (int i = 0; i < 4; i++)
        #pragma unroll
        for (int j = 0; j < 4; j++) acc[i][j] = (f32x4){0.f, 0.f, 0.f, 0.f};

    int r_in = lane >> 3;
    int cgo = ((lane & 7) ^ r_in) * 8;
    const __bf16* gA = A2 + (size_t)(bm + wid * 32 + r_in) * K2 + k_begin + cgo;
    const __bf16* gB = B2 + (size_t)(bn + wid * 32 + r_in) * K2 + k_begin + cgo;
    char* AhB = (char*)AhS; char* AlB = (char*)AlS;
    char* BhB = (char*)BhS; char* BlB = (char*)BlS;
    int lbw = wid * 4096;
    size_t row8 = 8 * K2;

    int ra = lane & 15, q = lane >> 4;
    int aoff[4][2], boff[4][2];
    #pragma unroll
    for (int i = 0; i < 4; i++) {
        #pragma unroll
        for (int kh = 0; kh < 2; kh++) {
            int chunk = ((kh << 2) | q) ^ (ra & 7);
            aoff[i][kh] = (wm + i * 16 + ra) * 64 + chunk * 8;
            boff[i][kh] = (wn + i * 16 + ra) * 64 + chunk * 8;
        }
    }
    const __bf16* AhE = (const __bf16*)AhS;
    const __bf16* AlE = (const __bf16*)AlS;
    const __bf16* BhE = (const __bf16*)BhS;
    const __bf16* BlE = (const __bf16*)BlS;

    for (int ks = 0; ks < nsteps; ks++) {
        __syncthreads();
        #pragma unroll
        for (int p = 0; p < 4; p++) {
            size_t go = p * row8;
            int lo = lbw + p * 1024;
            GLOAD_LDS(gA + go, AhB + lo);
            GLOAD_LDS(gA + go + K, AlB + lo);
            GLOAD_LDS(gB + go, BhB + lo);
            GLOAD_LDS(gB + go + K, BlB + lo);
        }
        gA += 64; gB += 64;
        __syncthreads();

        #pragma unroll
        for (int kh = 0; kh < 2; kh++) {
            bf16x8 ah[4], al[4];
            #pragma unroll
            for (int mi = 0; mi < 4; mi++) {
                ah[mi] = *(const bf16x8*)(AhE + aoff[mi][kh]);
                al[mi] = *(const bf16x8*)(AlE + aoff[mi][kh]);
            }
            #pragma unroll
            for (int ni = 0; ni < 4; ni++) {
                bf16x8 bh = *(const bf16x8*)(BhE + boff[ni][kh]);
                bf16x8 bl = *(const bf16x8*)(BlE + boff[ni][kh]);
                #pragma unroll
                for (int mi = 0; mi < 4; mi++) {
                    acc[mi][ni] = __builtin_amdgcn_mfma_f32_16x16x32_bf16(ah[mi], bh, acc[mi][ni], 0, 0, 0);
                    acc[mi][ni] = __builtin_amdgcn_mfma_f32_16x16x32_bf16(ah[mi], bl, acc[mi][ni], 0, 0, 0);
                    acc[mi][ni] = __builtin_amdgcn_mfma_f32_16x16x32_bf16(al[mi], bh, acc[mi][ni], 0, 0, 0);
                }
            }
        }
    }

    if (!LOGITS) {
        float* Cb = C + (size_t)blockIdx.z * M * N;
        #pragma unroll
        for (int mi = 0; mi < 4; mi++) {
            #pragma unroll
            for (int ni = 0; ni < 4; ni++) {
                int r0 = bm + wm + mi * 16 + q * 4;
                int c0 = bn + wn + ni * 16 + ra;
                Cb[(size_t)(r0 + 0) * N + c0] = acc[mi][ni][0];
                Cb[(size_t)(r0 + 1) * N + c0] = acc[mi][ni][1];
                Cb[(size_t)(r0 + 2) * N + c0] = acc[mi][ni][2];
                Cb[(size_t)(r0 + 3) * N + c0] = acc[mi][ni][3];
            }
        }
    } else {
        #pragma unroll
        for (int mi = 0; mi < 4; mi++) {
            #pragma unroll
            for (int ni = 0; ni < 4; ni++) {
                int cl = wn + ni * 16 + ra;
                float cn = cnL[cl];
                #pragma unroll
                for (int i = 0; i < 4; i++) {
                    int rl = wm + mi * 16 + q * 4 + i;
                    float sq = rnL[rl] + cn - 2.f * acc[mi][ni][i];
                    float d = sqrtf(fmaxf(sq, 1e-12f));
                    C[(size_t)(bm + rl) * N + bn + cl] = -TEMP * d;
                }
            }
        }
    }
}

// -- K_fuse2: [0,1024): reduce8 partials + split + norm + preds
//             [1024,3072): conv_norm(sf) wave-per-row -> sf2
__global__ __launch_bounds__(256) void k_fuse2(const float* __restrict__ parts,
                                               const float* __restrict__ sf,
                                               const float* __restrict__ W,
                                               const float* __restrict__ bias,
                                               __bf16* __restrict__ xsrc2,
                                               __bf16* __restrict__ sf2,
                                               float* __restrict__ nx2_,
                                               float* __restrict__ ns_,
                                               float* __restrict__ preds) {
    __shared__ float red[4][NC + 1];
    int b = blockIdx.x;
    if (b >= B_ROWS) {
        int wid = threadIdx.x >> 6;
        conv_norm_row_wave(sf, (b - B_ROWS) * 4 + wid, sf2, ns_);
        return;
    }
    int row = b;
    int c = threadIdx.x * 4;
    size_t off = (size_t)row * DIM + c;
    float4 s = make_float4(0.f, 0.f, 0.f, 0.f);
    #pragma unroll
    for (int z = 0; z < 8; z++) {
        float4 v = *(const float4*)(parts + (size_t)z * (B_ROWS * DIM) + off);
        s.x += v.x; s.y += v.y; s.z += v.z; s.w += v.w;
    }
    bf16x4 h, l;
    h[0] = split_hi(s.x); l[0] = split_lo(s.x);
    h[1] = split_hi(s.y); l[1] = split_lo(s.y);
    h[2] = split_hi(s.z); l[2] = split_lo(s.z);
    h[3] = split_hi(s.w); l[3] = split_lo(s.w);
    *(bf16x4*)(xsrc2 + (size_t)row * 2048 + c) = h;
    *(bf16x4*)(xsrc2 + (size_t)row * 2048 + 1024 + c) = l;
    float accn = s.x * s.x + s.y * s.y + s.z * s.z + s.w * s.w;
    float accp[NC];
    #pragma unroll
    for (int cc = 0; cc < NC; cc++)
        accp[cc] = s.x * W[(c + 0) * NC + cc] + s.y * W[(c + 1) * NC + cc]
                 + s.z * W[(c + 2) * NC + cc] + s.w * W[(c + 3) * NC + cc];
    accn = wave_sum(accn);
    #pragma unroll
    for (int cc = 0; cc < NC; cc++) accp[cc] = wave_sum(accp[cc]);
    int lane = threadIdx.x & 63, wid = threadIdx.x >> 6;
    if (lane == 0) {
        red[wid][0] = accn;
        #pragma unroll
        for (int cc = 0; cc < NC; cc++) red[wid][1 + cc] = accp[cc];
    }
    __syncthreads();
    if (threadIdx.x == 0) {
        nx2_[row] = red[0][0] + red[1][0] + red[2][0] + red[3][0];
        float lo[NC];
        float m = -1e30f;
        #pragma unroll
        for (int cc = 0; cc < NC; cc++) {
            lo[cc] = red[0][1 + cc] + red[1][1 + cc] + red[2][1 + cc] + red[3][1 + cc]
                   + bias[cc];
            m = fmaxf(m, lo[cc]);
        }
        float ssum = 0.f;
        #pragma unroll
        for (int cc = 0; cc < NC; cc++) {
            lo[cc] = __expf(lo[cc] - m);
            ssum += lo[cc];
        }
        float inv = 1.0f / ssum;
        #pragma unroll
        for (int cc = 0; cc < NC; cc++) preds[(size_t)row * NC + cc] = lo[cc] * inv;
    }
}

// ------ feature softmax (vectorized float4) -> split-bf16 w ------------------
__global__ __launch_bounds__(256) void k_softmax_w2(const float* __restrict__ S,
                                                    __bf16* __restrict__ w2) {
    int row = blockIdx.x;
    const float4* sr = (const float4*)(S + (size_t)row * NT);   // 2048 float4
    float4 vals[NT / 1024];                                      // 8
    float lmax = -1e30f;
    #pragma unroll
    for (int u = 0; u < NT / 1024; u++) {
        float4 v = sr[threadIdx.x + u * 256];
        vals[u] = v;
        lmax = fmaxf(fmaxf(fmaxf(v.x, v.y), fmaxf(v.z, v.w)), lmax);
    }
    __shared__ float sm[4];
    __shared__ float ss[4];
    int lane = threadIdx.x & 63, wid = threadIdx.x >> 6;
    float wm = wave_max(lmax);
    if (lane == 0) sm[wid] = wm;
    __syncthreads();
    float bmax = fmaxf(fmaxf(sm[0], sm[1]), fmaxf(sm[2], sm[3]));
    float lsum = 0.f;
    #pragma unroll
    for (int u = 0; u < NT / 1024; u++) {
        float4 v = vals[u];
        v.x = __expf(v.x - bmax); v.y = __expf(v.y - bmax);
        v.z = __expf(v.z - bmax); v.w = __expf(v.w - bmax);
        vals[u] = v;
        lsum += v.x + v.y + v.z + v.w;
    }
    float wsumv = wave_sum(lsum);
    if (lane == 0) ss[wid] = wsumv;
    __syncthreads();
    float inv = 1.0f / (ss[0] + ss[1] + ss[2] + ss[3]);
    __bf16* wr = w2 + (size_t)row * 16384;
    #pragma unroll
    for (int u = 0; u < NT / 1024; u++) {
        int j = (threadIdx.x + u * 256) * 4;
        float4 v = vals[u];
        v.x *= inv; v.y *= inv; v.z *= inv; v.w *= inv;
        bf16x4 h, l;
        h[0] = split_hi(v.x); l[0] = split_lo(v.x);
        h[1] = split_hi(v.y); l[1] = split_lo(v.y);
        h[2] = split_hi(v.z); l[2] = split_lo(v.z);
        h[3] = split_hi(v.w); l[3] = split_lo(v.w);
        *(bf16x4*)(wr + j) = h;
        *(bf16x4*)(wr + 8192 + j) = l;
    }
}

// ------- label softmax + y, 2 rows/block, float4-vectorized ------------------
// logits = S[row][j] - TEMP * sum_c preds[row][c]*M2Tt[c][j]
__global__ __launch_bounds__(256) void k_lab_softmax_y(const float* __restrict__ S,
                                                       const float* __restrict__ predsG,
                                                       const float* __restrict__ M2Tt,
                                                       const float* __restrict__ atlt,
                                                       float* __restrict__ y) {
    int r0 = blockIdx.x * 2, r1 = r0 + 1;
    float pr0[NC], pr1[NC];
    #pragma unroll
    for (int c = 0; c < NC; c++) {
        pr0[c] = predsG[(size_t)r0 * NC + c];
        pr1[c] = predsG[(size_t)r1 * NC + c];
    }
    const float4* s0 = (const float4*)(S + (size_t)r0 * NS);
    const float4* s1 = (const float4*)(S + (size_t)r1 * NS);
    const float4* M2 = (const float4*)M2Tt;    // [NC][2048]
    const float4* AT = (const float4*)atlt;    // [NC][2048]
    float4 v0[NS / 1024], v1[NS / 1024];       // 8 each
    float m0 = -1e30f, m1 = -1e30f;
    #pragma unroll
    for (int u = 0; u < NS / 1024; u++) {
        int j4 = threadIdx.x + u * 256;
        float4 a = s0[j4], b = s1[j4];
        float4 lab0 = make_float4(0.f, 0.f, 0.f, 0.f);
        float4 lab1 = make_float4(0.f, 0.f, 0.f, 0.f);
        #pragma unroll
        for (int c = 0; c < NC; c++) {
            float4 mv = M2[c * 2048 + j4];
            lab0.x += pr0[c] * mv.x; lab0.y += pr0[c] * mv.y;
            lab0.z += pr0[c] * mv.z; lab0.w += pr0[c] * mv.w;
            lab1.x += pr1[c] * mv.x; lab1.y += pr1[c] * mv.y;
            lab1.z += pr1[c] * mv.z; lab1.w += pr1[c] * mv.w;
        }
        a.x -= TEMP * lab0.x; a.y -= TEMP * lab0.y;
        a.z -= TEMP * lab0.z; a.w -= TEMP * lab0.w;
        b.x -= TEMP * lab1.x; b.y -= TEMP * lab1.y;
        b.z -= TEMP * lab1.z; b.w -= TEMP * lab1.w;
        v0[u] = a; v1[u] = b;
        m0 = fmaxf(m0, fmaxf(fmaxf(a.x, a.y), fmaxf(a.z, a.w)));
        m1 = fmaxf(m1, fmaxf(fmaxf(b.x, b.y), fmaxf(b.z, b.w)));
    }
    __shared__ float sm[2][4];
    __shared__ float ss[2][4];
    __shared__ float yred[4][2][NC];
    int lane = threadIdx.x & 63, wid = threadIdx.x >> 6;
    float wm0 = wave_max(m0), wm1 = wave_max(m1);
    if (lane == 0) { sm[0][wid] = wm0; sm[1][wid] = wm1; }
    __syncthreads();
    float bm0 = fmaxf(fmaxf(sm[0][0], sm[0][1]), fmaxf(sm[0][2], sm[0][3]));
    float bm1 = fmaxf(fmaxf(sm[1][0], sm[1][1]), fmaxf(sm[1][2], sm[1][3]));
    float ls0 = 0.f, ls1 = 0.f;
    #pragma unroll
    for (int u = 0; u < NS / 1024; u++) {
        float4 a = v0[u], b = v1[u];
        a.x = __expf(a.x - bm0); a.y = __expf(a.y - bm0);
        a.z = __expf(a.z - bm0); a.w = __expf(a.w - bm0);
        b.x = __expf(b.x - bm1); b.y = __expf(b.y - bm1);
        b.z = __expf(b.z - bm1); b.w = __expf(b.w - bm1);
        v0[u] = a; v1[u] = b;
        ls0 += a.x + a.y + a.z + a.w;
        ls1 += b.x + b.y + b.z + b.w;
    }
    float ws0 = wave_sum(ls0), ws1 = wave_sum(ls1);
    if (lane == 0) { ss[0][wid] = ws0; ss[1][wid] = ws1; }
    __syncthreads();
    float inv0 = 1.0f / (ss[0][0] + ss[0][1] + ss[0][2] + ss[0][3]);
    float inv1 = 1.0f / (ss[1][0] + ss[1][1] + ss[1][2] + ss[1][3]);
    float y0[NC] = {}, y1[NC] = {};
    #pragma unroll
    for (int u = 0; u < NS / 1024; u++) {
        int j4 = threadIdx.x + u * 256;
        float4 a = v0[u], b = v1[u];
        #pragma unroll
        for (int c = 0; c < NC; c++) {
            float4 av = AT[c * 2048 + j4];
            y0[c] += a.x * av.x + a.y * av.y + a.z * av.z + a.w * av.w;
            y1[c] += b.x * av.x + b.y * av.y + b.z * av.z + b.w * av.w;
        }
    }
    #pragma unroll
    for (int c = 0; c < NC; c++) {
        y0[c] = wave_sum(y0[c]) * inv0;
        y1[c] = wave_sum(y1[c]) * inv1;
    }
    if (lane == 0) {
        #pragma unroll
        for (int c = 0; c < NC; c++) { yred[wid][0][c] = y0[c]; yred[wid][1][c] = y1[c]; }
    }
    __syncthreads();
    if (threadIdx.x < 2 * NC) {
        int r = threadIdx.x / NC, c = threadIdx.x - r * NC;
        y[(size_t)(r0 + r) * NC + c] = yred[0][r][c] + yred[1][r][c] + yred[2][r][c] + yred[3][r][c];
    }
}

extern "C" void kernel_launch(void* const* d_in, const int* in_sizes, int n_in,
                              void* d_out, int out_size, void* d_ws, size_t ws_size,
                              hipStream_t stream) {
    const float* x    = (const float*)d_in[0];
    const float* tf   = (const float*)d_in[1];
    const float* asf  = (const float*)d_in[2];
    const float* sf   = (const float*)d_in[3];
    const float* shdl = (const float*)d_in[4];
    const float* atl  = (const float*)d_in[5];
    const float* sld  = (const float*)d_in[6];
    const float* W    = (const float*)d_in[7];
    const float* bias = (const float*)d_in[8];
    float* y = (float*)d_out;

    char* wsb = (char*)d_ws;
    // Region lifetimes (32 MiB each):
    //  R0 @0:  S (G1 out) -> parts (G2 out) -> S (G3 out)
    //  R1 @32: tf2 (until G1) -> asfT2 (conv2t out, until G2)
    //  R2 @64: w2 (until G2) -> sf2 (k_fuse2 out, until G3)
    float*  S     = (float*)(wsb);
    float*  parts = (float*)(wsb);
    __bf16* tf2   = (__bf16*)(wsb + (32u << 20));
    __bf16* asfT2 = (__bf16*)(wsb + (32u << 20));
    __bf16* w2    = (__bf16*)(wsb + (64u << 20));
    __bf16* sf2   = (__bf16*)(wsb + (64u << 20));
    __bf16* x2    = (__bf16*)(wsb + (96u << 20));
    __bf16* xsrc2 = (__bf16*)(wsb + (100u << 20));
    float*  nt_   = (float*)(wsb + (108u << 20));
    float*  ns_   = nt_ + NT;
    float*  nx_   = ns_ + NS;
    float*  nx2_  = nx_ + B_ROWS;
    float*  preds = nx2_ + B_ROWS;
    float*  M2Tt  = preds + B_ROWS * NC;
    float*  atlt  = M2Tt + NS * NC;

    // K0: conv_norm(x) + conv_norm(tf) wave-per-row + prep_labels
    k_prep0<<<256 + 2048 + NS / 256, 256, 0, stream>>>(x, tf, sld, shdl, atl,
                                                       x2, tf2, nx_, nt_, M2Tt, atlt);

    // G1: S = logits(-TEMP*d(x, tf))   -> R0
    {
        dim3 g(NT / 128, B_ROWS / 128, 1);
        k_gemm3<true><<<g, 256, 0, stream>>>(x2, tf2, S, B_ROWS, NT, DIM, DIM,
                                             nx_, nt_);
    }
    // w_feat softmax -> split-bf16 w2 (R2)
    k_softmax_w2<<<B_ROWS, 256, 0, stream>>>(S, w2);
    // conv2t(asf) -> asfT2 (R1, tf2 dead)
    k_conv2t<<<2048, 256, 0, stream>>>(asf, asfT2);
    // G2: parts[z] = w2 @ asfT2^T  (split-K x8) -> R0 (S dead)
    {
        dim3 g(DIM / 128, B_ROWS / 128, 8);
        k_gemm3<false><<<g, 256, 0, stream>>>(w2, asfT2, parts, B_ROWS, DIM, NT, NT / 8,
                                              nullptr, nullptr);
    }
    // K_fuse2: reduce8+split+norm+preds (reads R0) AND conv_norm(sf) -> R2 (w2 dead)
    k_fuse2<<<B_ROWS + 2048, 256, 0, stream>>>(parts, sf, W, bias, xsrc2, sf2,
                                               nx2_, ns_, preds);

    // G3: S = logits(-TEMP*d(xsrc, sf))  -> R0 (parts dead)
    {
        dim3 g(NS / 128, B_ROWS / 128, 1);
        k_gemm3<true><<<g, 256, 0, stream>>>(xsrc2, sf2, S, B_ROWS, NS, DIM, DIM,
                                             nx2_, ns_);
    }
    // label softmax (with M2T term) + y, 2 rows/block
    k_lab_softmax_y<<<B_ROWS / 2, 256, 0, stream>>>(S, preds, M2Tt, atlt, y);
}